// Round 1
// baseline (155.596 us; speedup 1.0000x reference)
//
#include <hip/hip_runtime.h>

// ResRnn closed-form (verified by previous session, absmax 0.03125 = bf16
// quantization floor):
//   out[t,b,64k+o] = LIN^(k+1) * input[t-k,b,o]              (k <= t)
//   out[t,b,64k+o] = LIN^(t+1) * 1e-5 * init[64(k-t-1)+o]    (k >  t)
//
// v6: fill-style streaming rewrite. The poison fill in the same timed graph
// hits 6.7 TB/s with purely sequential stores; v5 (LDS round-trip + 16
// scattered 4KB chunks per block) ran ~2.2 TB/s effective. v6 removes LDS,
// barrier, and scatter entirely:
//   - block = (t, b-half): 1024 blocks, each writes a 128 KB fully
//     CONTIGUOUS span of out[t][b0..b0+31][*] (one 4KB block-wide store per
//     iteration, marching sequentially).
//   - thread j owns (k=j>>4, o4=j&15); scale LIN^(k+1) is loop-invariant.
//   - input read directly from global: 8 MB total, L2/L3-resident (each
//     input row is re-read by the 16 t's above it — served by cache, not
//     LDS). XCD-chunked t mapping (t = (bid&7)*64 | ...) keeps those 16
//     consumer blocks on the same XCD's L2.
//   - k>t lanes (only blocks t<15) read init ONCE and store a constant.

#define SEQ    512
#define BATCH  64
#define SW     1024
#define LINF   0.99999f
#define BSPLIT 2               // b-halves per t
#define NB     (BATCH/BSPLIT)  // 32 batches per block

typedef float vf4 __attribute__((ext_vector_type(4)));

__global__ __launch_bounds__(256) void resrnn_v6(
    const float* __restrict__ input,        // [SEQ, BATCH, 64]
    const float* __restrict__ init_stream,  // [SW]
    float* __restrict__ out)                // [SEQ, BATCH, SW]
{
    int bid = blockIdx.x;                 // 0..1023
    int xcd = bid & 7;
    int idx = bid >> 3;                   // 0..127
    int t   = (xcd << 6) | (idx >> 1);    // 0..511, 64-consecutive-t per XCD
    int b0  = (idx & 1) * NB;

    int j  = threadIdx.x;                 // 0..255
    int k  = j >> 4;                      // shift block 0..15
    int o4 = j & 15;                      // float4 within 64-wide input elem

    // s = LIN^(k+1), exact sequential-multiply chain (matches reference)
    float s = LINF;
    #pragma unroll
    for (int i = 0; i < 15; ++i) s = (i < k) ? s * LINF : s;

    int g = t - k;                        // source input row

    // out float4 base: (t*64 + b0)*256 + j ; +256 per batch iteration
    vf4* outp = (vf4*)out + (((size_t)(t << 6) + b0) << 8) + j;

    if (g < 0) {
        // init-stream lanes (only in blocks t < 15): constant across b
        float si = 1e-5f * __powf(LINF, (float)(t + 1));
        vf4 v = *(const vf4*)(init_stream + (((-g - 1) << 6) + (o4 << 2)));
        v *= si;
        #pragma unroll 8
        for (int b = 0; b < NB; ++b)
            outp[b << 8] = v;
    } else {
        // src float4: row g, batch b0+b, offset o4 ; +64 floats per iteration
        const float* src = input + ((size_t)((g << 6) + b0) << 6) + (o4 << 2);
        #pragma unroll 8
        for (int b = 0; b < NB; ++b)
            outp[b << 8] = *(const vf4*)(src + (b << 6)) * s;
    }
}

extern "C" void kernel_launch(void* const* d_in, const int* in_sizes, int n_in,
                              void* d_out, int out_size, void* d_ws, size_t ws_size,
                              hipStream_t stream) {
    const float* input       = (const float*)d_in[0];  // [512,64,64]
    const float* init_stream = (const float*)d_in[1];  // [1024]
    float* out               = (float*)d_out;          // [512,64,1024]

    const int blocks = SEQ * BSPLIT;                   // 1024
    resrnn_v6<<<blocks, 256, 0, stream>>>(input, init_stream, out);
}

// Round 2
// 154.813 us; speedup vs baseline: 1.0051x; 1.0051x over previous
//
#include <hip/hip_runtime.h>

// ResRnn closed-form (verified: absmax 0.03125 = bf16 quantization floor):
//   out[t,b,64k+o] = LIN^(k+1) * input[t-k,b,o]              (k <= t)
//   out[t,b,64k+o] = LIN^(t+1) * 1e-5 * init[64(k-t-1)+o]    (k >  t)
//
// v7: v6's contiguous-span structure at v5's grid size (TLP experiment).
//   v5 (2048 blk, LDS-staged, scattered 4KB stores): kernel ~65 us
//   v6 (1024 blk, direct L2 reads, 128KB contiguous): kernel ~74 us
// Hypothesis: streaming stores are TLP-limited, not pattern-limited.
// v7 = 2048 blocks, block = (t, b-quarter): each block writes a 64 KB
// fully contiguous span of out[t][b0..b0+15][*]; unroll 8 keeps VGPR low
// so all 8 blocks/CU are resident -> 32 waves/CU (2x v6).
// Reads come straight from global: 8 MB input, XCD-chunked t mapping keeps
// each XCD's working set (~1.3 MB) in its private L2.

#define SEQ    512
#define BATCH  64
#define SW     1024
#define LINF   0.99999f
#define NB     16              // batches per block (quarter of 64)

typedef float vf4 __attribute__((ext_vector_type(4)));

__global__ __launch_bounds__(256) void resrnn_v7(
    const float* __restrict__ input,        // [SEQ, BATCH, 64]
    const float* __restrict__ init_stream,  // [SW]
    float* __restrict__ out)                // [SEQ, BATCH, SW]
{
    int bid = blockIdx.x;                 // 0..2047
    int xcd = bid & 7;                    // HW round-robins bid%8 -> XCD
    int idx = bid >> 3;                   // 0..255
    int t   = (xcd << 6) | (idx >> 2);    // 64 consecutive t per XCD
    int b0  = (idx & 3) << 4;             // 0,16,32,48

    int j  = threadIdx.x;                 // 0..255
    int k  = j >> 4;                      // shift block 0..15
    int o4 = j & 15;                      // float4 within 64-wide input elem

    // s = LIN^(k+1), exact sequential-multiply chain (matches reference)
    float s = LINF;
    #pragma unroll
    for (int i = 0; i < 15; ++i) s = (i < k) ? s * LINF : s;

    int g = t - k;                        // source input row

    // out float4 base: (t*64 + b0)*256 + j ; +256 float4 (4KB) per batch iter
    vf4* outp = (vf4*)out + (((size_t)(t << 6) + b0) << 8) + j;

    if (g < 0) {
        // init-stream lanes (only blocks with t < 15): constant across b
        float si = 1e-5f * __powf(LINF, (float)(t + 1));
        vf4 v = *(const vf4*)(init_stream + (((-g - 1) << 6) + (o4 << 2)));
        v *= si;
        #pragma unroll 8
        for (int b = 0; b < NB; ++b)
            outp[b << 8] = v;
    } else {
        // src float4: row g, batch b0+b, offset o4 ; +64 floats per iter
        const float* src = input + ((size_t)((g << 6) + b0) << 6) + (o4 << 2);
        #pragma unroll 8
        for (int b = 0; b < NB; ++b)
            outp[b << 8] = *(const vf4*)(src + (b << 6)) * s;
    }
}

extern "C" void kernel_launch(void* const* d_in, const int* in_sizes, int n_in,
                              void* d_out, int out_size, void* d_ws, size_t ws_size,
                              hipStream_t stream) {
    const float* input       = (const float*)d_in[0];  // [512,64,64]
    const float* init_stream = (const float*)d_in[1];  // [1024]
    float* out               = (float*)d_out;          // [512,64,1024]

    const int blocks = SEQ * 4;                        // 2048
    resrnn_v7<<<blocks, 256, 0, stream>>>(input, init_stream, out);
}